// Round 1
// baseline (224.070 us; speedup 1.0000x reference)
//
#include <hip/hip_runtime.h>
#include <math.h>

#define N_PTS     131072
#define G_NUMS    30
#define G_SIZE    100
#define PT_STRIDE (N_PTS / G_NUMS)   // 4369
#define TPB       512
#define NWAVES    (TPB / 64)
#define R_KEEP    8
#define EQ_CAP    64

__device__ __forceinline__ float dist2f(float px, float py, float pz,
                                        float qx, float qy, float qz) {
    float dx = px - qx, dy = py - qy, dz = pz - qz;
    return fmaf(dx, dx, fmaf(dy, dy, dz * dz));
}

__device__ __forceinline__ void insert_cand(float (&kv)[R_KEEP], int (&ki)[R_KEEP],
                                            float d, int i) {
    kv[R_KEEP - 1] = d; ki[R_KEEP - 1] = i;
#pragma unroll
    for (int j = R_KEEP - 1; j > 0; --j) {
        if (kv[j] < kv[j - 1]) {
            float tv = kv[j]; kv[j] = kv[j - 1]; kv[j - 1] = tv;
            int ti = ki[j]; ki[j] = ki[j - 1]; ki[j - 1] = ti;
        }
    }
}

// Block-wide sum of per-thread counts. Two barriers (WAR + visibility).
__device__ __forceinline__ unsigned block_count(unsigned my, unsigned* s_part,
                                                int lane, int wid) {
    int c = (int)my;
#pragma unroll
    for (int off = 32; off > 0; off >>= 1) c += __shfl_down(c, off);
    __syncthreads();
    if (lane == 0) s_part[wid] = (unsigned)c;
    __syncthreads();
    unsigned tot = 0;
    for (int w = 0; w < NWAVES; w++) tot += s_part[w];
    return tot;
}

template <int PASS>
__global__ __launch_bounds__(TPB)
void knn_kernel(const float* __restrict__ pts, const float* __restrict__ queries,
                float* __restrict__ out_mean, float* __restrict__ out_cov, int B) {
    __shared__ unsigned s_part[NWAVES];
    __shared__ int s_selidx[G_SIZE];
    __shared__ int s_eqidx[EQ_CAP];
    __shared__ int s_ltc, s_eqc;
    __shared__ float s_acc[3];
    __shared__ float s_cov[6];
    __shared__ float s_q[3];

    const int blk = blockIdx.x;
    const int b = blk / G_NUMS;
    const int g = blk % G_NUMS;
    const float* __restrict__ P = pts + (size_t)b * (N_PTS * 3);
    const int tid = threadIdx.x;
    const int lane = tid & 63, wid = tid >> 6;

    if (tid == 0) {
        if (PASS == 1) {
            const float* q = P + (size_t)g * PT_STRIDE * 3;
            s_q[0] = q[0]; s_q[1] = q[1]; s_q[2] = q[2];
        } else {
            const float* q = queries + (size_t)blk * 3;
            s_q[0] = q[0]; s_q[1] = q[1]; s_q[2] = q[2];
        }
        s_ltc = 0; s_eqc = 0;
    }
    __syncthreads();
    const float qx = s_q[0], qy = s_q[1], qz = s_q[2];

    // ---- scan: per-thread top-R in sorted registers ----
    float kv[R_KEEP]; int ki[R_KEEP];
#pragma unroll
    for (int j = 0; j < R_KEEP; j++) { kv[j] = INFINITY; ki[j] = -1; }

    const float4* __restrict__ P4 = (const float4*)P;
    for (int grp = tid; grp < N_PTS / 4; grp += TPB) {
        float4 f0 = P4[3 * grp + 0];
        float4 f1 = P4[3 * grp + 1];
        float4 f2 = P4[3 * grp + 2];
        int i0 = grp * 4;
        float d0 = dist2f(f0.x, f0.y, f0.z, qx, qy, qz);
        float d1 = dist2f(f0.w, f1.x, f1.y, qx, qy, qz);
        float d2 = dist2f(f1.z, f1.w, f2.x, qx, qy, qz);
        float d3 = dist2f(f2.y, f2.z, f2.w, qx, qy, qz);
        if (d0 < kv[R_KEEP - 1]) insert_cand(kv, ki, d0, i0 + 0);
        if (d1 < kv[R_KEEP - 1]) insert_cand(kv, ki, d1, i0 + 1);
        if (d2 < kv[R_KEEP - 1]) insert_cand(kv, ki, d2, i0 + 2);
        if (d3 < kv[R_KEEP - 1]) insert_cand(kv, ki, d3, i0 + 3);
    }

    unsigned ku[R_KEEP];
#pragma unroll
    for (int j = 0; j < R_KEEP; j++) ku[j] = __float_as_uint(kv[j]);

    // ---- exact kth value via bitwise binary search over candidates ----
    unsigned cur = 0u;
    for (int bit = 31; bit >= 0; --bit) {
        unsigned test = cur | (1u << bit);
        unsigned c = 0;
#pragma unroll
        for (int j = 0; j < R_KEEP; j++) c += (ku[j] < test) ? 1u : 0u;
        unsigned tot = block_count(c, s_part, lane, wid);
        if (tot < G_SIZE) cur = test;
    }
    const unsigned T = cur;   // bit pattern of 100th smallest d2

    // ---- gather selected indices ----
    if (tid < G_SIZE) s_selidx[tid] = 0;
    __syncthreads();
#pragma unroll
    for (int j = 0; j < R_KEEP; j++) {
        if (ku[j] < T) {
            int p = atomicAdd(&s_ltc, 1);
            if (p < G_SIZE) s_selidx[p] = ki[j];
        } else if (ku[j] == T) {
            int p = atomicAdd(&s_eqc, 1);
            if (p < EQ_CAP) s_eqidx[p] = ki[j];
        }
    }
    __syncthreads();
    if (tid == 0) {
        int ltc = s_ltc; if (ltc > G_SIZE) ltc = G_SIZE;
        int need = G_SIZE - ltc;
        int ec = s_eqc; if (ec > EQ_CAP) ec = EQ_CAP;
        for (int a2 = 0; a2 < need && a2 < ec; ++a2) {
            int best = a2;
            for (int j = a2 + 1; j < ec; ++j)
                if (s_eqidx[j] < s_eqidx[best]) best = j;
            int t = s_eqidx[best]; s_eqidx[best] = s_eqidx[a2]; s_eqidx[a2] = t;
            s_selidx[ltc + a2] = s_eqidx[a2];
        }
    }
    if (tid < 3) s_acc[tid] = 0.f;
    if (tid < 6) s_cov[tid] = 0.f;
    __syncthreads();

    // ---- mean of selected 100 ----
    float px = 0.f, py = 0.f, pz = 0.f;
    if (tid < G_SIZE) {
        int i = s_selidx[tid];
        px = P[3 * i]; py = P[3 * i + 1]; pz = P[3 * i + 2];
        atomicAdd(&s_acc[0], px);
        atomicAdd(&s_acc[1], py);
        atomicAdd(&s_acc[2], pz);
    }
    __syncthreads();

    if (PASS == 1) {
        if (tid < 3) out_mean[(size_t)blk * 3 + tid] = s_acc[tid] * (1.0f / G_SIZE);
    } else {
        float mx = s_acc[0] * (1.0f / G_SIZE);
        float my = s_acc[1] * (1.0f / G_SIZE);
        float mz = s_acc[2] * (1.0f / G_SIZE);
        if (tid < G_SIZE) {
            float x = px - mx, y = py - my, z = pz - mz;
            atomicAdd(&s_cov[0], x * x);
            atomicAdd(&s_cov[1], x * y);
            atomicAdd(&s_cov[2], x * z);
            atomicAdd(&s_cov[3], y * y);
            atomicAdd(&s_cov[4], y * z);
            atomicAdd(&s_cov[5], z * z);
        }
        __syncthreads();
        if (tid < 6) out_cov[(size_t)blk * 6 + tid] = s_cov[tid] * (1.0f / G_SIZE);
    }
}

// ---- 3x3 symmetric eigensolve (Jacobi, double) ----
__device__ void eig3(const float cf[6], double lam_out[3], double dir_out[3]) {
    double a[3][3], v[3][3];
    a[0][0] = cf[0]; a[0][1] = cf[1]; a[0][2] = cf[2];
    a[1][0] = cf[1]; a[1][1] = cf[3]; a[1][2] = cf[4];
    a[2][0] = cf[2]; a[2][1] = cf[4]; a[2][2] = cf[5];
    for (int i = 0; i < 3; i++)
        for (int j = 0; j < 3; j++) v[i][j] = (i == j) ? 1.0 : 0.0;

    for (int sweep = 0; sweep < 12; sweep++) {
        double off = a[0][1] * a[0][1] + a[0][2] * a[0][2] + a[1][2] * a[1][2];
        if (off == 0.0) break;
        for (int p = 0; p < 2; p++) {
            for (int q = p + 1; q < 3; q++) {
                double apq = a[p][q];
                if (apq == 0.0) continue;
                double app = a[p][p], aqq = a[q][q];
                double theta = (aqq - app) / (2.0 * apq);
                double t = (theta >= 0.0 ? 1.0 : -1.0) /
                           (fabs(theta) + sqrt(theta * theta + 1.0));
                double c = 1.0 / sqrt(t * t + 1.0);
                double s = t * c;
                a[p][p] = app - t * apq;
                a[q][q] = aqq + t * apq;
                a[p][q] = 0.0; a[q][p] = 0.0;
                for (int r = 0; r < 3; r++) {
                    if (r == p || r == q) continue;
                    double arp = a[r][p], arq = a[r][q];
                    a[r][p] = c * arp - s * arq; a[p][r] = a[r][p];
                    a[r][q] = s * arp + c * arq; a[q][r] = a[r][q];
                }
                for (int r = 0; r < 3; r++) {
                    double vrp = v[r][p], vrq = v[r][q];
                    v[r][p] = c * vrp - s * vrq;
                    v[r][q] = s * vrp + c * vrq;
                }
            }
        }
    }
    double l0 = a[0][0], l1 = a[1][1], l2 = a[2][2];
    int i0 = 0, i1 = 1, i2 = 2;
    if (l0 > l1) { double t = l0; l0 = l1; l1 = t; int ti = i0; i0 = i1; i1 = ti; }
    if (l1 > l2) { double t = l1; l1 = l2; l2 = t; int ti = i1; i1 = i2; i2 = ti; }
    if (l0 > l1) { double t = l0; l0 = l1; l1 = t; int ti = i0; i0 = i1; i1 = ti; }
    lam_out[0] = l0; lam_out[1] = l1; lam_out[2] = l2;
    dir_out[0] = v[0][i2]; dir_out[1] = v[1][i2]; dir_out[2] = v[2][i2];
}

__global__ __launch_bounds__(256)
void finalize_kernel(const float* __restrict__ gmeans, const float* __restrict__ covs,
                     float* __restrict__ out, int B) {
    const int tid = threadIdx.x;
    const int NG = B * G_NUMS;   // 240
    __shared__ float s_dir[256][3];
    __shared__ float s_gm[256][3];
    __shared__ float s_pe[4];
    __shared__ float s_ps[4];

    float et = 0.f;
    if (tid < NG) {
        float cf[6];
#pragma unroll
        for (int j = 0; j < 6; j++) cf[j] = covs[tid * 6 + j];
        double lam[3], dir[3];
        eig3(cf, lam, dir);
        double denom = lam[0] + lam[1] + lam[2] + 1e-9;
        et = (float)((lam[2] - lam[1]) / denom);
        s_dir[tid][0] = (float)dir[0];
        s_dir[tid][1] = (float)dir[1];
        s_dir[tid][2] = (float)dir[2];
        s_gm[tid][0] = gmeans[tid * 3 + 0];
        s_gm[tid][1] = gmeans[tid * 3 + 1];
        s_gm[tid][2] = gmeans[tid * 3 + 2];
    }
    __syncthreads();

    float st = 0.f;
    if (tid < NG) {
        int b = tid / G_NUMS, g = tid % G_NUMS;
        float gx = s_gm[tid][0], gy = s_gm[tid][1], gz = s_gm[tid][2];
        float bd = 3.4e38f; int bj = 0;
        for (int gg = 0; gg < G_NUMS; gg++) {
            if (gg == g) continue;
            int o = b * G_NUMS + gg;
            float dx = gx - s_gm[o][0];
            float dy = gy - s_gm[o][1];
            float dz = gz - s_gm[o][2];
            float d = dx * dx + dy * dy + dz * dz;
            if (d < bd) { bd = d; bj = gg; }
        }
        int o = b * G_NUMS + bj;
        float cosv = s_dir[tid][0] * s_dir[o][0] +
                     s_dir[tid][1] * s_dir[o][1] +
                     s_dir[tid][2] * s_dir[o][2];
        st = 1.f - cosv * cosv;
    }

    float e = et, s2 = st;
#pragma unroll
    for (int off = 32; off > 0; off >>= 1) {
        e += __shfl_down(e, off);
        s2 += __shfl_down(s2, off);
    }
    int lane = tid & 63, wid = tid >> 6;
    if (lane == 0) { s_pe[wid] = e; s_ps[wid] = s2; }
    __syncthreads();
    if (tid == 0) {
        float se = 0.f, ss = 0.f;
        for (int w = 0; w < 4; w++) { se += s_pe[w]; ss += s_ps[w]; }
        out[0] = -se / (float)B + ss / (float)NG;
    }
}

extern "C" void kernel_launch(void* const* d_in, const int* in_sizes, int n_in,
                              void* d_out, int out_size, void* d_ws, size_t ws_size,
                              hipStream_t stream) {
    const float* pts = (const float*)d_in[0];
    float* out = (float*)d_out;
    float* ws = (float*)d_ws;
    int B = in_sizes[0] / (N_PTS * 3);   // 8
    float* gmeans = ws;                   // B*G_NUMS*3 floats
    float* covs = ws + (size_t)B * G_NUMS * 3;  // B*G_NUMS*6 floats

    dim3 grid(B * G_NUMS);
    knn_kernel<1><<<grid, TPB, 0, stream>>>(pts, nullptr, gmeans, nullptr, B);
    knn_kernel<2><<<grid, TPB, 0, stream>>>(pts, gmeans, nullptr, covs, B);
    finalize_kernel<<<1, 256, 0, stream>>>(gmeans, covs, out, B);
}

// Round 2
// 212.589 us; speedup vs baseline: 1.0540x; 1.0540x over previous
//
#include <hip/hip_runtime.h>
#include <math.h>

#define N_PTS     131072
#define G_NUMS    30
#define G_SIZE    100
#define PT_STRIDE (N_PTS / G_NUMS)   // 4369
#define TPB       512
#define NWAVES    (TPB / 64)
#define BINS      4096
#define SHIFT     20
#define TIE_CAP   256

__device__ __forceinline__ float dist2f(float px, float py, float pz,
                                        float qx, float qy, float qz) {
    float dx = px - qx, dy = py - qy, dz = pz - qz;
    return fmaf(dx, dx, fmaf(dy, dy, dz * dz));
}

// Fused kernel: one block per (batch, group). Phase 0: select 100-NN of the
// strided center -> group mean. Phase 1: select 100-NN of that mean -> cov.
// Selection = branchless 2-scan radix-histogram (4096 bins on bits>>20).
__global__ __launch_bounds__(TPB)
void fused_knn_kernel(const float* __restrict__ pts,
                      float* __restrict__ out_mean, float* __restrict__ out_cov,
                      int B) {
    __shared__ unsigned s_hist[BINS];
    __shared__ unsigned s_wsum[NWAVES];
    __shared__ unsigned s_T, s_Clt;
    __shared__ int s_nd, s_nt;
    __shared__ float s_selx[G_SIZE], s_sely[G_SIZE], s_selz[G_SIZE];
    __shared__ unsigned long long s_tkey[TIE_CAP];
    __shared__ float s_tx[TIE_CAP], s_ty[TIE_CAP], s_tz[TIE_CAP];
    __shared__ float s_acc[3];
    __shared__ float s_cov[6];
    __shared__ float s_q[3];

    const int blk = blockIdx.x;
    const int b = blk % B;          // batch-per-XCD swizzle (round-robin dispatch)
    const int g = blk / B;
    const int gi = b * G_NUMS + g;  // b-major index for finalize layout
    const float* __restrict__ P = pts + (size_t)b * (N_PTS * 3);
    const float4* __restrict__ P4 = (const float4*)P;
    const int tid = threadIdx.x;
    const int lane = tid & 63, wid = tid >> 6;

    if (tid == 0) {
        const float* q = P + (size_t)g * PT_STRIDE * 3;
        s_q[0] = q[0]; s_q[1] = q[1]; s_q[2] = q[2];
    }

    for (int phase = 0; phase < 2; ++phase) {
        __syncthreads();            // s_q ready; previous phase fully done
        const float qx = s_q[0], qy = s_q[1], qz = s_q[2];

        // ---- zero shared state ----
        for (int j = tid; j < BINS; j += TPB) s_hist[j] = 0u;
        if (tid == 0) { s_nd = 0; s_nt = 0; }
        if (tid < 3) s_acc[tid] = 0.f;
        if (tid < 6) s_cov[tid] = 0.f;
        __syncthreads();

        // ---- scan 1: histogram of d2 bit-prefix ----
#pragma unroll 4
        for (int grp = tid; grp < N_PTS / 4; grp += TPB) {
            float4 f0 = P4[3 * grp + 0];
            float4 f1 = P4[3 * grp + 1];
            float4 f2 = P4[3 * grp + 2];
            unsigned u0 = __float_as_uint(dist2f(f0.x, f0.y, f0.z, qx, qy, qz));
            unsigned u1 = __float_as_uint(dist2f(f0.w, f1.x, f1.y, qx, qy, qz));
            unsigned u2 = __float_as_uint(dist2f(f1.z, f1.w, f2.x, qx, qy, qz));
            unsigned u3 = __float_as_uint(dist2f(f2.y, f2.z, f2.w, qx, qy, qz));
            atomicAdd(&s_hist[u0 >> SHIFT], 1u);
            atomicAdd(&s_hist[u1 >> SHIFT], 1u);
            atomicAdd(&s_hist[u2 >> SHIFT], 1u);
            atomicAdd(&s_hist[u3 >> SHIFT], 1u);
        }
        __syncthreads();

        // ---- block prefix-scan over 4096 bins -> threshold bin T ----
        unsigned hv[8];
        unsigned csum = 0;
#pragma unroll
        for (int j = 0; j < 8; j++) { hv[j] = s_hist[tid * 8 + j]; csum += hv[j]; }
        unsigned inc = csum;
#pragma unroll
        for (int off = 1; off < 64; off <<= 1) {
            unsigned n = __shfl_up(inc, off);
            if (lane >= off) inc += n;
        }
        if (lane == 63) s_wsum[wid] = inc;
        __syncthreads();
        unsigned base = 0;
        for (int w = 0; w < wid; w++) base += s_wsum[w];
        unsigned c = base + inc - csum;   // exclusive prefix before this chunk
#pragma unroll
        for (int j = 0; j < 8; j++) {
            if (c < G_SIZE && c + hv[j] >= G_SIZE) { s_T = tid * 8 + j; s_Clt = c; }
            c += hv[j];
        }
        __syncthreads();
        const unsigned T = s_T;
        const unsigned defb = T << SHIFT;  // bits < defb => definitely selected

        // ---- scan 2: collect definite + tie candidates ----
#pragma unroll 2
        for (int grp = tid; grp < N_PTS / 4; grp += TPB) {
            float4 f0 = P4[3 * grp + 0];
            float4 f1 = P4[3 * grp + 1];
            float4 f2 = P4[3 * grp + 2];
            float x[4], y[4], z[4];
            x[0] = f0.x; y[0] = f0.y; z[0] = f0.z;
            x[1] = f0.w; y[1] = f1.x; z[1] = f1.y;
            x[2] = f1.z; y[2] = f1.w; z[2] = f2.x;
            x[3] = f2.y; y[3] = f2.z; z[3] = f2.w;
#pragma unroll
            for (int j = 0; j < 4; j++) {
                unsigned u = __float_as_uint(dist2f(x[j], y[j], z[j], qx, qy, qz));
                if (u < defb) {
                    int p = atomicAdd(&s_nd, 1);
                    s_selx[p] = x[j]; s_sely[p] = y[j]; s_selz[p] = z[j];
                } else if ((u >> SHIFT) == T) {
                    int p = atomicAdd(&s_nt, 1);
                    if (p < TIE_CAP) {
                        s_tkey[p] = ((unsigned long long)u << 32) | (unsigned)(grp * 4 + j);
                        s_tx[p] = x[j]; s_ty[p] = y[j]; s_tz[p] = z[j];
                    }
                }
            }
        }
        __syncthreads();

        // ---- resolve ties: need smallest (bits, idx) pairs to fill to 100 ----
        if (tid == 0) {
            int nd = s_nd;
            int need = G_SIZE - nd;
            int ec = s_nt; if (ec > TIE_CAP) ec = TIE_CAP;
            for (int a = 0; a < need && a < ec; ++a) {
                int best = a;
                for (int j = a + 1; j < ec; ++j)
                    if (s_tkey[j] < s_tkey[best]) best = j;
                unsigned long long tk = s_tkey[best]; s_tkey[best] = s_tkey[a]; s_tkey[a] = tk;
                float t;
                t = s_tx[best]; s_tx[best] = s_tx[a]; s_tx[a] = t;
                t = s_ty[best]; s_ty[best] = s_ty[a]; s_ty[a] = t;
                t = s_tz[best]; s_tz[best] = s_tz[a]; s_tz[a] = t;
                s_selx[nd + a] = s_tx[a];
                s_sely[nd + a] = s_ty[a];
                s_selz[nd + a] = s_tz[a];
            }
        }
        __syncthreads();

        // ---- mean over the 100 selected ----
        float px = 0.f, py = 0.f, pz = 0.f;
        if (tid < G_SIZE) {
            px = s_selx[tid]; py = s_sely[tid]; pz = s_selz[tid];
            atomicAdd(&s_acc[0], px);
            atomicAdd(&s_acc[1], py);
            atomicAdd(&s_acc[2], pz);
        }
        __syncthreads();

        if (phase == 0) {
            if (tid < 3) {
                float m = s_acc[tid] * (1.0f / G_SIZE);
                out_mean[(size_t)gi * 3 + tid] = m;
                s_q[tid] = m;   // query for phase 1 (barrier at loop top)
            }
        } else {
            float mx = s_acc[0] * (1.0f / G_SIZE);
            float my = s_acc[1] * (1.0f / G_SIZE);
            float mz = s_acc[2] * (1.0f / G_SIZE);
            if (tid < G_SIZE) {
                float x = px - mx, y = py - my, z = pz - mz;
                atomicAdd(&s_cov[0], x * x);
                atomicAdd(&s_cov[1], x * y);
                atomicAdd(&s_cov[2], x * z);
                atomicAdd(&s_cov[3], y * y);
                atomicAdd(&s_cov[4], y * z);
                atomicAdd(&s_cov[5], z * z);
            }
            __syncthreads();
            if (tid < 6) out_cov[(size_t)gi * 6 + tid] = s_cov[tid] * (1.0f / G_SIZE);
        }
    }
}

// ---- 3x3 symmetric eigensolve (Jacobi, double) ----
__device__ void eig3(const float cf[6], double lam_out[3], double dir_out[3]) {
    double a[3][3], v[3][3];
    a[0][0] = cf[0]; a[0][1] = cf[1]; a[0][2] = cf[2];
    a[1][0] = cf[1]; a[1][1] = cf[3]; a[1][2] = cf[4];
    a[2][0] = cf[2]; a[2][1] = cf[4]; a[2][2] = cf[5];
    for (int i = 0; i < 3; i++)
        for (int j = 0; j < 3; j++) v[i][j] = (i == j) ? 1.0 : 0.0;

    for (int sweep = 0; sweep < 12; sweep++) {
        double off = a[0][1] * a[0][1] + a[0][2] * a[0][2] + a[1][2] * a[1][2];
        if (off == 0.0) break;
        for (int p = 0; p < 2; p++) {
            for (int q = p + 1; q < 3; q++) {
                double apq = a[p][q];
                if (apq == 0.0) continue;
                double app = a[p][p], aqq = a[q][q];
                double theta = (aqq - app) / (2.0 * apq);
                double t = (theta >= 0.0 ? 1.0 : -1.0) /
                           (fabs(theta) + sqrt(theta * theta + 1.0));
                double c = 1.0 / sqrt(t * t + 1.0);
                double s = t * c;
                a[p][p] = app - t * apq;
                a[q][q] = aqq + t * apq;
                a[p][q] = 0.0; a[q][p] = 0.0;
                for (int r = 0; r < 3; r++) {
                    if (r == p || r == q) continue;
                    double arp = a[r][p], arq = a[r][q];
                    a[r][p] = c * arp - s * arq; a[p][r] = a[r][p];
                    a[r][q] = s * arp + c * arq; a[q][r] = a[r][q];
                }
                for (int r = 0; r < 3; r++) {
                    double vrp = v[r][p], vrq = v[r][q];
                    v[r][p] = c * vrp - s * vrq;
                    v[r][q] = s * vrp + c * vrq;
                }
            }
        }
    }
    double l0 = a[0][0], l1 = a[1][1], l2 = a[2][2];
    int i0 = 0, i1 = 1, i2 = 2;
    if (l0 > l1) { double t = l0; l0 = l1; l1 = t; int ti = i0; i0 = i1; i1 = ti; }
    if (l1 > l2) { double t = l1; l1 = l2; l2 = t; int ti = i1; i1 = i2; i2 = ti; }
    if (l0 > l1) { double t = l0; l0 = l1; l1 = t; int ti = i0; i0 = i1; i1 = ti; }
    lam_out[0] = l0; lam_out[1] = l1; lam_out[2] = l2;
    dir_out[0] = v[0][i2]; dir_out[1] = v[1][i2]; dir_out[2] = v[2][i2];
}

__global__ __launch_bounds__(256)
void finalize_kernel(const float* __restrict__ gmeans, const float* __restrict__ covs,
                     float* __restrict__ out, int B) {
    const int tid = threadIdx.x;
    const int NG = B * G_NUMS;   // 240
    __shared__ float s_dir[256][3];
    __shared__ float s_gm[256][3];
    __shared__ float s_pe[4];
    __shared__ float s_ps[4];

    float et = 0.f;
    if (tid < NG) {
        float cf[6];
#pragma unroll
        for (int j = 0; j < 6; j++) cf[j] = covs[tid * 6 + j];
        double lam[3], dir[3];
        eig3(cf, lam, dir);
        double denom = lam[0] + lam[1] + lam[2] + 1e-9;
        et = (float)((lam[2] - lam[1]) / denom);
        s_dir[tid][0] = (float)dir[0];
        s_dir[tid][1] = (float)dir[1];
        s_dir[tid][2] = (float)dir[2];
        s_gm[tid][0] = gmeans[tid * 3 + 0];
        s_gm[tid][1] = gmeans[tid * 3 + 1];
        s_gm[tid][2] = gmeans[tid * 3 + 2];
    }
    __syncthreads();

    float st = 0.f;
    if (tid < NG) {
        int b = tid / G_NUMS, g = tid % G_NUMS;
        float gx = s_gm[tid][0], gy = s_gm[tid][1], gz = s_gm[tid][2];
        float bd = 3.4e38f; int bj = 0;
        for (int gg = 0; gg < G_NUMS; gg++) {
            if (gg == g) continue;
            int o = b * G_NUMS + gg;
            float dx = gx - s_gm[o][0];
            float dy = gy - s_gm[o][1];
            float dz = gz - s_gm[o][2];
            float d = dx * dx + dy * dy + dz * dz;
            if (d < bd) { bd = d; bj = gg; }
        }
        int o = b * G_NUMS + bj;
        float cosv = s_dir[tid][0] * s_dir[o][0] +
                     s_dir[tid][1] * s_dir[o][1] +
                     s_dir[tid][2] * s_dir[o][2];
        st = 1.f - cosv * cosv;
    }

    float e = et, s2 = st;
#pragma unroll
    for (int off = 32; off > 0; off >>= 1) {
        e += __shfl_down(e, off);
        s2 += __shfl_down(s2, off);
    }
    int lane = tid & 63, wid = tid >> 6;
    if (lane == 0) { s_pe[wid] = e; s_ps[wid] = s2; }
    __syncthreads();
    if (tid == 0) {
        float se = 0.f, ss = 0.f;
        for (int w = 0; w < 4; w++) { se += s_pe[w]; ss += s_ps[w]; }
        out[0] = -se / (float)B + ss / (float)NG;
    }
}

extern "C" void kernel_launch(void* const* d_in, const int* in_sizes, int n_in,
                              void* d_out, int out_size, void* d_ws, size_t ws_size,
                              hipStream_t stream) {
    const float* pts = (const float*)d_in[0];
    float* out = (float*)d_out;
    float* ws = (float*)d_ws;
    int B = in_sizes[0] / (N_PTS * 3);   // 8
    float* gmeans = ws;                          // B*G_NUMS*3 floats
    float* covs = ws + (size_t)B * G_NUMS * 3;   // B*G_NUMS*6 floats

    dim3 grid(B * G_NUMS);
    fused_knn_kernel<<<grid, TPB, 0, stream>>>(pts, gmeans, covs, B);
    finalize_kernel<<<1, 256, 0, stream>>>(gmeans, covs, out, B);
}

// Round 3
// 162.194 us; speedup vs baseline: 1.3815x; 1.3107x over previous
//
#include <hip/hip_runtime.h>
#include <math.h>

#define N_PTS     131072
#define G_NUMS    30
#define G_SIZE    100
#define PT_STRIDE (N_PTS / G_NUMS)   // 4369
#define TPB       512
#define NWAVES    (TPB / 64)
#define BINS      4096
#define SHIFT     20
#define SAMPLE_GRPS 1024             // first 4096 points as iid sample
#define RANK_CUT  32                 // 32nd-smallest sample -> tau (P(fail) ~ 1e-25)
#define CAP       3072               // survivor capacity (~11 sigma above mean ~1024)
#define TIE_CAP   64

__device__ __forceinline__ float dist2f(float px, float py, float pz,
                                        float qx, float qy, float qz) {
    float dx = px - qx, dy = py - qy, dz = pz - qz;
    return fmaf(dx, dx, fmaf(dy, dy, dz * dz));
}

// Find smallest bin T such that cumulative count through T >= rank.
// s_hist must be populated; uses s_wsum scratch; one result via *s_T.
__device__ __forceinline__ unsigned find_bin(unsigned* s_hist, unsigned* s_wsum,
                                             unsigned* s_T, unsigned rank,
                                             int tid, int lane, int wid) {
    unsigned hv[8], csum = 0;
#pragma unroll
    for (int j = 0; j < 8; j++) { hv[j] = s_hist[tid * 8 + j]; csum += hv[j]; }
    unsigned inc = csum;
#pragma unroll
    for (int off = 1; off < 64; off <<= 1) {
        unsigned n = __shfl_up(inc, off);
        if (lane >= off) inc += n;
    }
    __syncthreads();                  // protect s_wsum reuse across calls
    if (lane == 63) s_wsum[wid] = inc;
    __syncthreads();
    unsigned base = 0;
    for (int w = 0; w < wid; w++) base += s_wsum[w];
    unsigned c = base + inc - csum;   // exclusive prefix before this thread's chunk
#pragma unroll
    for (int j = 0; j < 8; j++) {
        if (c < rank && c + hv[j] >= rank) *s_T = (unsigned)(tid * 8 + j);
        c += hv[j];
    }
    __syncthreads();
    return *s_T;
}

// One block per (batch, group). Phase 0: exact 100-NN of strided center -> mean.
// Phase 1: exact 100-NN of that mean -> covariance.
// Selection: sampled coarse threshold -> filter scan -> fine histogram select.
__global__ __launch_bounds__(TPB)
void fused_knn_kernel(const float* __restrict__ pts,
                      float* __restrict__ out_mean, float* __restrict__ out_cov,
                      int B) {
    __shared__ unsigned s_hist[BINS];
    __shared__ unsigned s_wsum[NWAVES];
    __shared__ unsigned s_T;
    __shared__ int s_ns, s_nd, s_nt;
    __shared__ unsigned s_u[CAP];
    __shared__ int s_idx[CAP];
    __shared__ int s_sel[G_SIZE];
    __shared__ unsigned s_tu[TIE_CAP];
    __shared__ int s_ti[TIE_CAP];
    __shared__ float s_acc[3], s_cov[6], s_q[3];

    const int blk = blockIdx.x;
    const int b = blk % B;           // batch-per-XCD swizzle (L2 locality, verified r2)
    const int g = blk / B;
    const int gi = b * G_NUMS + g;   // b-major for finalize
    const float* __restrict__ P = pts + (size_t)b * (N_PTS * 3);
    const float4* __restrict__ P4 = (const float4*)P;
    const int tid = threadIdx.x;
    const int lane = tid & 63, wid = tid >> 6;

    if (tid == 0) {
        const float* q = P + (size_t)g * PT_STRIDE * 3;
        s_q[0] = q[0]; s_q[1] = q[1]; s_q[2] = q[2];
    }

    for (int phase = 0; phase < 2; ++phase) {
        __syncthreads();             // s_q ready; previous phase's LDS fully consumed
        const float qx = s_q[0], qy = s_q[1], qz = s_q[2];

        for (int j = tid; j < BINS; j += TPB) s_hist[j] = 0u;
        if (tid == 0) { s_ns = 0; s_nd = 0; s_nt = 0; s_T = 0u; }
        if (tid < 3) s_acc[tid] = 0.f;
        if (tid < 6) s_cov[tid] = 0.f;
        __syncthreads();

        // ---- sample scan: 4096 distances -> coarse histogram ----
        for (int grp = tid; grp < SAMPLE_GRPS; grp += TPB) {
            float4 f0 = P4[3 * grp + 0];
            float4 f1 = P4[3 * grp + 1];
            float4 f2 = P4[3 * grp + 2];
            unsigned u0 = __float_as_uint(dist2f(f0.x, f0.y, f0.z, qx, qy, qz));
            unsigned u1 = __float_as_uint(dist2f(f0.w, f1.x, f1.y, qx, qy, qz));
            unsigned u2 = __float_as_uint(dist2f(f1.z, f1.w, f2.x, qx, qy, qz));
            unsigned u3 = __float_as_uint(dist2f(f2.y, f2.z, f2.w, qx, qy, qz));
            atomicAdd(&s_hist[u0 >> SHIFT], 1u);
            atomicAdd(&s_hist[u1 >> SHIFT], 1u);
            atomicAdd(&s_hist[u2 >> SHIFT], 1u);
            atomicAdd(&s_hist[u3 >> SHIFT], 1u);
        }
        __syncthreads();
        unsigned Tc = find_bin(s_hist, s_wsum, &s_T, RANK_CUT, tid, lane, wid);
        const unsigned tau = (Tc >= BINS - 1) ? 0xFFFFFFFFu : ((Tc + 1) << SHIFT);
        // re-zero hist for the fine pass (everyone already read what they need)
        for (int j = tid; j < BINS; j += TPB) s_hist[j] = 0u;
        __syncthreads();

        // ---- full scan: pure filter, rare compaction (hit rate ~1/128) ----
#pragma unroll 4
        for (int grp = tid; grp < N_PTS / 4; grp += TPB) {
            float4 f0 = P4[3 * grp + 0];
            float4 f1 = P4[3 * grp + 1];
            float4 f2 = P4[3 * grp + 2];
            unsigned u0 = __float_as_uint(dist2f(f0.x, f0.y, f0.z, qx, qy, qz));
            unsigned u1 = __float_as_uint(dist2f(f0.w, f1.x, f1.y, qx, qy, qz));
            unsigned u2 = __float_as_uint(dist2f(f1.z, f1.w, f2.x, qx, qy, qz));
            unsigned u3 = __float_as_uint(dist2f(f2.y, f2.z, f2.w, qx, qy, qz));
            int i0 = grp * 4;
            if (u0 < tau) { int p = atomicAdd(&s_ns, 1); if (p < CAP) { s_u[p] = u0; s_idx[p] = i0; } }
            if (u1 < tau) { int p = atomicAdd(&s_ns, 1); if (p < CAP) { s_u[p] = u1; s_idx[p] = i0 + 1; } }
            if (u2 < tau) { int p = atomicAdd(&s_ns, 1); if (p < CAP) { s_u[p] = u2; s_idx[p] = i0 + 2; } }
            if (u3 < tau) { int p = atomicAdd(&s_ns, 1); if (p < CAP) { s_u[p] = u3; s_idx[p] = i0 + 3; } }
        }
        __syncthreads();
        int S = s_ns; if (S > CAP) S = CAP;

        // ---- fine histogram over survivors: exact rank-100 bin ----
        unsigned hb = 32u - (unsigned)__clz(tau - 1u);       // bit-length of tau-1
        unsigned s2 = hb > 12u ? hb - 12u : 0u;              // (tau-1)>>s2 < 4096
        for (int i = tid; i < S; i += TPB) atomicAdd(&s_hist[s_u[i] >> s2], 1u);
        __syncthreads();
        unsigned T2 = find_bin(s_hist, s_wsum, &s_T, G_SIZE, tid, lane, wid);
        const unsigned lo = T2 << s2;

        // ---- collect definite + ties ----
        for (int i = tid; i < S; i += TPB) {
            unsigned u = s_u[i];
            if (u < lo) {
                int p = atomicAdd(&s_nd, 1);
                if (p < G_SIZE) s_sel[p] = s_idx[i];
            } else if ((u >> s2) == T2) {
                int p = atomicAdd(&s_nt, 1);
                if (p < TIE_CAP) { s_tu[p] = u; s_ti[p] = s_idx[i]; }
            }
        }
        __syncthreads();
        if (tid == 0) {
            int nd = s_nd; if (nd > G_SIZE) nd = G_SIZE;
            int need = G_SIZE - nd;
            int ec = s_nt; if (ec > TIE_CAP) ec = TIE_CAP;
            for (int a = 0; a < need && a < ec; ++a) {
                int best = a;
                for (int j = a + 1; j < ec; ++j)
                    if (s_tu[j] < s_tu[best] ||
                        (s_tu[j] == s_tu[best] && s_ti[j] < s_ti[best])) best = j;
                unsigned tu = s_tu[best]; s_tu[best] = s_tu[a]; s_tu[a] = tu;
                int ti = s_ti[best]; s_ti[best] = s_ti[a]; s_ti[a] = ti;
                s_sel[nd + a] = s_ti[a];
            }
        }
        __syncthreads();

        // ---- mean / covariance over the exact 100 ----
        float px = 0.f, py = 0.f, pz = 0.f;
        if (tid < G_SIZE) {
            const float* pp = P + 3 * (size_t)s_sel[tid];
            px = pp[0]; py = pp[1]; pz = pp[2];
            atomicAdd(&s_acc[0], px);
            atomicAdd(&s_acc[1], py);
            atomicAdd(&s_acc[2], pz);
        }
        __syncthreads();

        if (phase == 0) {
            if (tid < 3) {
                float m = s_acc[tid] * (1.0f / G_SIZE);
                out_mean[(size_t)gi * 3 + tid] = m;
                s_q[tid] = m;          // phase-1 query (loop-top barrier covers)
            }
        } else {
            float mx = s_acc[0] * (1.0f / G_SIZE);
            float my = s_acc[1] * (1.0f / G_SIZE);
            float mz = s_acc[2] * (1.0f / G_SIZE);
            if (tid < G_SIZE) {
                float x = px - mx, y = py - my, z = pz - mz;
                atomicAdd(&s_cov[0], x * x);
                atomicAdd(&s_cov[1], x * y);
                atomicAdd(&s_cov[2], x * z);
                atomicAdd(&s_cov[3], y * y);
                atomicAdd(&s_cov[4], y * z);
                atomicAdd(&s_cov[5], z * z);
            }
            __syncthreads();
            if (tid < 6) out_cov[(size_t)gi * 6 + tid] = s_cov[tid] * (1.0f / G_SIZE);
        }
    }
}

// ---- 3x3 symmetric eigensolve (Jacobi, double) ----
__device__ void eig3(const float cf[6], double lam_out[3], double dir_out[3]) {
    double a[3][3], v[3][3];
    a[0][0] = cf[0]; a[0][1] = cf[1]; a[0][2] = cf[2];
    a[1][0] = cf[1]; a[1][1] = cf[3]; a[1][2] = cf[4];
    a[2][0] = cf[2]; a[2][1] = cf[4]; a[2][2] = cf[5];
    for (int i = 0; i < 3; i++)
        for (int j = 0; j < 3; j++) v[i][j] = (i == j) ? 1.0 : 0.0;

    for (int sweep = 0; sweep < 12; sweep++) {
        double off = a[0][1] * a[0][1] + a[0][2] * a[0][2] + a[1][2] * a[1][2];
        if (off == 0.0) break;
        for (int p = 0; p < 2; p++) {
            for (int q = p + 1; q < 3; q++) {
                double apq = a[p][q];
                if (apq == 0.0) continue;
                double app = a[p][p], aqq = a[q][q];
                double theta = (aqq - app) / (2.0 * apq);
                double t = (theta >= 0.0 ? 1.0 : -1.0) /
                           (fabs(theta) + sqrt(theta * theta + 1.0));
                double c = 1.0 / sqrt(t * t + 1.0);
                double s = t * c;
                a[p][p] = app - t * apq;
                a[q][q] = aqq + t * apq;
                a[p][q] = 0.0; a[q][p] = 0.0;
                for (int r = 0; r < 3; r++) {
                    if (r == p || r == q) continue;
                    double arp = a[r][p], arq = a[r][q];
                    a[r][p] = c * arp - s * arq; a[p][r] = a[r][p];
                    a[r][q] = s * arp + c * arq; a[q][r] = a[r][q];
                }
                for (int r = 0; r < 3; r++) {
                    double vrp = v[r][p], vrq = v[r][q];
                    v[r][p] = c * vrp - s * vrq;
                    v[r][q] = s * vrp + c * vrq;
                }
            }
        }
    }
    double l0 = a[0][0], l1 = a[1][1], l2 = a[2][2];
    int i0 = 0, i1 = 1, i2 = 2;
    if (l0 > l1) { double t = l0; l0 = l1; l1 = t; int ti = i0; i0 = i1; i1 = ti; }
    if (l1 > l2) { double t = l1; l1 = l2; l2 = t; int ti = i1; i1 = i2; i2 = ti; }
    if (l0 > l1) { double t = l0; l0 = l1; l1 = t; int ti = i0; i0 = i1; i1 = ti; }
    lam_out[0] = l0; lam_out[1] = l1; lam_out[2] = l2;
    dir_out[0] = v[0][i2]; dir_out[1] = v[1][i2]; dir_out[2] = v[2][i2];
}

__global__ __launch_bounds__(256)
void finalize_kernel(const float* __restrict__ gmeans, const float* __restrict__ covs,
                     float* __restrict__ out, int B) {
    const int tid = threadIdx.x;
    const int NG = B * G_NUMS;   // 240
    __shared__ float s_dir[256][3];
    __shared__ float s_gm[256][3];
    __shared__ float s_pe[4];
    __shared__ float s_ps[4];

    float et = 0.f;
    if (tid < NG) {
        float cf[6];
#pragma unroll
        for (int j = 0; j < 6; j++) cf[j] = covs[tid * 6 + j];
        double lam[3], dir[3];
        eig3(cf, lam, dir);
        double denom = lam[0] + lam[1] + lam[2] + 1e-9;
        et = (float)((lam[2] - lam[1]) / denom);
        s_dir[tid][0] = (float)dir[0];
        s_dir[tid][1] = (float)dir[1];
        s_dir[tid][2] = (float)dir[2];
        s_gm[tid][0] = gmeans[tid * 3 + 0];
        s_gm[tid][1] = gmeans[tid * 3 + 1];
        s_gm[tid][2] = gmeans[tid * 3 + 2];
    }
    __syncthreads();

    float st = 0.f;
    if (tid < NG) {
        int b = tid / G_NUMS, g = tid % G_NUMS;
        float gx = s_gm[tid][0], gy = s_gm[tid][1], gz = s_gm[tid][2];
        float bd = 3.4e38f; int bj = 0;
        for (int gg = 0; gg < G_NUMS; gg++) {
            if (gg == g) continue;
            int o = b * G_NUMS + gg;
            float dx = gx - s_gm[o][0];
            float dy = gy - s_gm[o][1];
            float dz = gz - s_gm[o][2];
            float d = dx * dx + dy * dy + dz * dz;
            if (d < bd) { bd = d; bj = gg; }
        }
        int o = b * G_NUMS + bj;
        float cosv = s_dir[tid][0] * s_dir[o][0] +
                     s_dir[tid][1] * s_dir[o][1] +
                     s_dir[tid][2] * s_dir[o][2];
        st = 1.f - cosv * cosv;
    }

    float e = et, s2 = st;
#pragma unroll
    for (int off = 32; off > 0; off >>= 1) {
        e += __shfl_down(e, off);
        s2 += __shfl_down(s2, off);
    }
    int lane = tid & 63, wid = tid >> 6;
    if (lane == 0) { s_pe[wid] = e; s_ps[wid] = s2; }
    __syncthreads();
    if (tid == 0) {
        float se = 0.f, ss = 0.f;
        for (int w = 0; w < 4; w++) { se += s_pe[w]; ss += s_ps[w]; }
        out[0] = -se / (float)B + ss / (float)NG;
    }
}

extern "C" void kernel_launch(void* const* d_in, const int* in_sizes, int n_in,
                              void* d_out, int out_size, void* d_ws, size_t ws_size,
                              hipStream_t stream) {
    const float* pts = (const float*)d_in[0];
    float* out = (float*)d_out;
    float* ws = (float*)d_ws;
    int B = in_sizes[0] / (N_PTS * 3);   // 8
    float* gmeans = ws;                          // B*G_NUMS*3 floats
    float* covs = ws + (size_t)B * G_NUMS * 3;   // B*G_NUMS*6 floats

    dim3 grid(B * G_NUMS);
    fused_knn_kernel<<<grid, TPB, 0, stream>>>(pts, gmeans, covs, B);
    finalize_kernel<<<1, 256, 0, stream>>>(gmeans, covs, out, B);
}